// Round 2
// baseline (381.032 us; speedup 1.0000x reference)
//
#include <hip/hip_runtime.h>
#include <stdint.h>

// ============================================================================
// CPM layer, bit-exact JAX reproduction.
//   B=8, C=8, H=W=1024. 8 checkerboard Metropolis half-steps.
//   RNG: threefry2x32. JAX_PARTITIONABLE selects the jax_threefry_partitionable
//   stream layout (default True in modern jax). Flip to 0 for legacy stream.
//
// Key chain (partitionable), per scan step t with step key s_t = cipher(base,(0,t)):
//   k1 = cipher(s_t,(0,0))          # dirs key (randint arg)
//   k2 = cipher(s_t,(0,1))          # uniform key
//   randint internally: kk1,kk2 = split(k1); dirs = random_bits(kk2) & 3
//     (span=4 -> multiplier = (2^16 % 4)^2 % 4 = 0 -> only lower_bits matter)
//   so  dkey = cipher(k1,(0,1)) ;  ukey = k2
//   random_bits(key,32,(B,H,W))[p] = o0^o1 of cipher(key,(0,p))
// ============================================================================

#define JAX_PARTITIONABLE 1

#define HW   1048576    // 1024*1024
#define BHWu 8388608u   // 8*HW
#define NHu  4194304u   // BHW/2

// ---------------------------------------------------------------------- RNG
__device__ __host__ __forceinline__ void tf2x32(uint32_t k0, uint32_t k1,
                                                uint32_t x0, uint32_t x1,
                                                uint32_t& o0, uint32_t& o1) {
  uint32_t k2 = k0 ^ k1 ^ 0x1BD11BDAu;
  x0 += k0; x1 += k1;
#define RDD(r) { x0 += x1; x1 = (x1 << (r)) | (x1 >> (32 - (r))); x1 ^= x0; }
  RDD(13) RDD(15) RDD(26) RDD(6)
  x0 += k1; x1 += k2 + 1u;
  RDD(17) RDD(29) RDD(16) RDD(24)
  x0 += k2; x1 += k0 + 2u;
  RDD(13) RDD(15) RDD(26) RDD(6)
  x0 += k0; x1 += k1 + 3u;
  RDD(17) RDD(29) RDD(16) RDD(24)
  x0 += k1; x1 += k2 + 4u;
  RDD(13) RDD(15) RDD(26) RDD(6)
  x0 += k2; x1 += k0 + 5u;
#undef RDD
  o0 = x0; o1 = x1;
}

// ------------------------------------------------- XLA-CPU Cephes expf clone
// Mirrors xla GenerateVF32Exp (Eigen3/Cephes pexp port).
// MulAdd -> fmaf (host JIT contracts on AVX2/FMA); Mul/Sub kept unfused.
// Final max(result, input) mirrors Eigen's pmax(pldexp(y,m), _x).
__device__ __forceinline__ float xla_expf(float input) {
  float x  = fmaxf(fminf(input, 88.3762626647950f), -88.3762626647949f);
  float fx = floorf(fmaf(x, 1.44269504088896341f, 0.5f));
  float tmp = __fmul_rn(0.693359375f, fx);
  float z   = __fmul_rn(-2.12194440e-4f, fx);
  x = __fsub_rn(x, tmp);
  x = __fsub_rn(x, z);
  z = __fmul_rn(x, x);
  float y = fmaf(x, 1.9875691500e-4f, 1.3981999507e-3f);
  y = fmaf(y, x, 8.3334519073e-3f);
  y = fmaf(y, x, 4.1665795894e-2f);
  y = fmaf(y, x, 1.6666665459e-1f);
  y = fmaf(y, x, 5.0000001201e-1f);
  y = fmaf(y, z, x);
  y = __fadd_rn(y, 1.0f);
  int n = (int)fx;
  float p2n = __int_as_float((n + 127) << 23);
  return fmaxf(__fmul_rn(y, p2n), input);
}

// ------------------------------------------------------------------- kernels
// prep: dH_NN = einsum('bchw,oc->bhwo') + bias  (Eigen no-FMA k-chain, acc=0,
// k ascending, bias added after) ; extract ids as u8.
__global__ __launch_bounds__(256) void prep(const float* __restrict__ X,
                                            const float* __restrict__ W,
                                            const float* __restrict__ Bb,
                                            float* __restrict__ dHNN,
                                            uint8_t* __restrict__ ids) {
  int p  = blockIdx.x * 256 + threadIdx.x;      // 0 .. BHW-1
  int b  = p >> 20;
  int yx = p & (HW - 1);
  const float* xp = X + ((size_t)b << 23) + yx; // b*C*HW + yx
  float xc[8];
#pragma unroll
  for (int c = 0; c < 8; c++) xc[c] = xp[(size_t)c << 20];
  float4 r;
#pragma unroll
  for (int o = 0; o < 4; o++) {
    float acc = 0.0f;
#pragma unroll
    for (int c = 0; c < 8; c++) acc = __fadd_rn(acc, __fmul_rn(xc[c], W[o * 8 + c]));
    ((float*)&r)[o] = __fadd_rn(acc, Bb[o]);
  }
  ((float4*)dHNN)[p] = r;
  ids[p] = (uint8_t)(int)xc[0];
}

// half_step: only active-parity pixels launched. In-place: neighbors of any
// active pixel are opposite parity -> never written this launch -> race-free.
__global__ __launch_bounds__(256) void half_step(uint8_t* __restrict__ ids,
                                                 const float* __restrict__ dHNN,
                                                 uint32_t dk0, uint32_t dk1,
                                                 uint32_t uk0, uint32_t uk1,
                                                 int sub) {
  int t   = blockIdx.x * 256 + threadIdx.x;   // 0 .. NH-1
  int row = t >> 9;                           // b*1024 + y
  int i   = t & 511;
  int b   = row >> 10;
  int y   = row & 1023;
  int x   = (i << 1) | ((y + sub) & 1);       // (y+x)%2 == sub
  int p   = (b << 20) | (y << 10) | x;

  uint32_t d0, d1, u0, u1, db, ub;
#if JAX_PARTITIONABLE
  // random_bits(key,32,(B,H,W))[p] = o0^o1 of cipher(key,(0,p))
  tf2x32(dk0, dk1, 0u, (uint32_t)p, d0, d1);
  db = d0 ^ d1;
  tf2x32(uk0, uk1, 0u, (uint32_t)p, u0, u1);
  ub = u0 ^ u1;
#else
  // legacy random_bits: counts=iota(BHW), halves -> lane pm=(p mod NH),
  // counter (pm, pm+NH); bits[p] = p<NH ? o0 : o1.
  uint32_t pm = (uint32_t)p & (NHu - 1u);
  tf2x32(dk0, dk1, pm, pm + NHu, d0, d1);
  db = ((uint32_t)p < NHu) ? d0 : d1;
  tf2x32(uk0, uk1, pm, pm + NHu, u0, u1);
  ub = ((uint32_t)p < NHu) ? u0 : u1;
#endif
  int dir = (int)(db & 3u);
  float u = __fsub_rn(__uint_as_float((ub >> 9) | 0x3F800000u), 1.0f);

  int yN = (y + 1) & 1023, yP = (y - 1) & 1023;
  int xN = (x + 1) & 1023, xP = (x - 1) & 1023;
  int base = b << 20;
  uint32_t c  = ids[p];
  uint32_t n0 = ids[base + (yN << 10) + x];    // roll(-1,0): ids[y+1]
  uint32_t n1 = ids[base + (yP << 10) + x];    // roll(+1,0): ids[y-1]
  uint32_t n2 = ids[base + (y << 10) + xN];    // roll(0,-1): ids[x+1]
  uint32_t n3 = ids[base + (y << 10) + xP];    // roll(0,+1): ids[x-1]
  uint32_t s  = (dir == 0) ? n0 : (dir == 1) ? n1 : (dir == 2) ? n2 : n3;
  int dadh = ((int)(n0 != s) + (n1 != s) + (n2 != s) + (n3 != s))
           - ((int)(n0 != c) + (n1 != c) + (n2 != c) + (n3 != c));
  float dH = __fadd_rn((float)dadh, dHNN[((size_t)p << 2) + dir]);
  if (u < xla_expf(-dH)) ids[p] = (uint8_t)s;
}

// finalize: out = X with channel0 <- ids. Overwrites the dH_NN scratch region.
__global__ __launch_bounds__(256) void finalize(const float* __restrict__ X,
                                                const uint8_t* __restrict__ ids,
                                                float* __restrict__ out) {
  int t = blockIdx.x * 256 + threadIdx.x;   // per float4, 16777216 total
  int e = t << 2;
  int c = (e >> 20) & 7;
  float4 r;
  if (c == 0) {
    int b  = e >> 23;
    int yx = e & (HW - 1);
    uchar4 v = *(const uchar4*)(ids + ((size_t)b << 20) + yx);
    r.x = (float)v.x; r.y = (float)v.y; r.z = (float)v.z; r.w = (float)v.w;
  } else {
    r = ((const float4*)X)[t];
  }
  ((float4*)out)[t] = r;
}

// --------------------------------------------------------------------- host
extern "C" void kernel_launch(void* const* d_in, const int* in_sizes, int n_in,
                              void* d_out, int out_size, void* d_ws, size_t ws_size,
                              hipStream_t stream) {
  const float* X  = (const float*)d_in[0];
  const float* W  = (const float*)d_in[1];
  const float* Bb = (const float*)d_in[2];
  float*   out  = (float*)d_out;
  float*   dHNN = (float*)d_out;          // first 134 MB of d_out as scratch
  uint8_t* ids  = (uint8_t*)d_ws;         // 8.4 MB

  prep<<<32768, 256, 0, stream>>>(X, W, Bb, dHNN, ids);

  // Host-side threefry key chain (deterministic, ~40 cipher calls).
  uint32_t bk0 = 0u, bk1 = 42u;           // jax.random.key(42)
  uint32_t keys[8][2];
#if JAX_PARTITIONABLE
  for (uint32_t t = 0; t < 8; t++)
    tf2x32(bk0, bk1, 0u, t, keys[t][0], keys[t][1]);   // fold-like split
#else
  {
    // split(base, 8): counts=iota(16): lane i = (i, 8+i) -> (A_i, B_i)
    // flat=[A0..A7,B0..B7]; key t = (flat[2t], flat[2t+1])
    uint32_t A[8], Bv[8];
    for (uint32_t i = 0; i < 8; i++) tf2x32(bk0, bk1, i, 8u + i, A[i], Bv[i]);
    for (int j = 0; j < 4; j++) { keys[j][0]     = A[2 * j];  keys[j][1]     = A[2 * j + 1]; }
    for (int j = 0; j < 4; j++) { keys[4 + j][0] = Bv[2 * j]; keys[4 + j][1] = Bv[2 * j + 1]; }
  }
#endif
  for (int t = 0; t < 8; t++) {
    uint32_t dk0, dk1, uk0, uk1;
#if JAX_PARTITIONABLE
    uint32_t k1a, k1b;
    tf2x32(keys[t][0], keys[t][1], 0u, 0u, k1a, k1b);  // k1 (randint arg key)
    tf2x32(keys[t][0], keys[t][1], 0u, 1u, uk0, uk1);  // k2 (uniform key)
    tf2x32(k1a, k1b, 0u, 1u, dk0, dk1);                // randint internal kk2
#else
    // split(s_t,2): lanes (0,2),(1,3): k1=(a0,a1), k2=(b0,b1)
    uint32_t a0, b0, a1, b1;
    tf2x32(keys[t][0], keys[t][1], 0u, 2u, a0, b0);
    tf2x32(keys[t][0], keys[t][1], 1u, 3u, a1, b1);
    uk0 = b0; uk1 = b1;                                 // k2 (uniform key)
    // randint internal split(k1,2) -> kk2 = (o1 lane0, o1 lane1)
    uint32_t c0, d0c, c1, d1c;
    tf2x32(a0, a1, 0u, 2u, c0, d0c);
    tf2x32(a0, a1, 1u, 3u, c1, d1c);
    dk0 = d0c; dk1 = d1c;
#endif
    half_step<<<16384, 256, 0, stream>>>(ids, dHNN, dk0, dk1, uk0, uk1, t & 1);
  }

  finalize<<<65536, 256, 0, stream>>>(X, ids, out);
  (void)in_sizes; (void)n_in; (void)out_size; (void)ws_size;
}

// Round 3
// 319.756 us; speedup vs baseline: 1.1916x; 1.1916x over previous
//
#include <hip/hip_runtime.h>
#include <stdint.h>

// ============================================================================
// CPM layer, bit-exact JAX reproduction. B=8, C=8, H=W=1024.
// Round 3: parity-packed dHNN (coalesced float4 read in half_step, half the
// stream), X pass-through folded into prep, tiny finalize. RNG/math unchanged
// from the PASSING round-2 kernel (bit-exact).
// ============================================================================

#define HW   1048576    // 1024*1024
#define BHWu 8388608u   // 8*HW
#define NHu  4194304u   // BHW/2 = active pixels per parity

// ---------------------------------------------------------------------- RNG
__device__ __host__ __forceinline__ void tf2x32(uint32_t k0, uint32_t k1,
                                                uint32_t x0, uint32_t x1,
                                                uint32_t& o0, uint32_t& o1) {
  uint32_t k2 = k0 ^ k1 ^ 0x1BD11BDAu;
  x0 += k0; x1 += k1;
#define RDD(r) { x0 += x1; x1 = (x1 << (r)) | (x1 >> (32 - (r))); x1 ^= x0; }
  RDD(13) RDD(15) RDD(26) RDD(6)
  x0 += k1; x1 += k2 + 1u;
  RDD(17) RDD(29) RDD(16) RDD(24)
  x0 += k2; x1 += k0 + 2u;
  RDD(13) RDD(15) RDD(26) RDD(6)
  x0 += k0; x1 += k1 + 3u;
  RDD(17) RDD(29) RDD(16) RDD(24)
  x0 += k1; x1 += k2 + 4u;
  RDD(13) RDD(15) RDD(26) RDD(6)
  x0 += k2; x1 += k0 + 5u;
#undef RDD
  o0 = x0; o1 = x1;
}

// ------------------------------------------------- XLA-CPU Cephes expf clone
__device__ __forceinline__ float xla_expf(float input) {
  float x  = fmaxf(fminf(input, 88.3762626647950f), -88.3762626647949f);
  float fx = floorf(fmaf(x, 1.44269504088896341f, 0.5f));
  float tmp = __fmul_rn(0.693359375f, fx);
  float z   = __fmul_rn(-2.12194440e-4f, fx);
  x = __fsub_rn(x, tmp);
  x = __fsub_rn(x, z);
  z = __fmul_rn(x, x);
  float y = fmaf(x, 1.9875691500e-4f, 1.3981999507e-3f);
  y = fmaf(y, x, 8.3334519073e-3f);
  y = fmaf(y, x, 4.1665795894e-2f);
  y = fmaf(y, x, 1.6666665459e-1f);
  y = fmaf(y, x, 5.0000001201e-1f);
  y = fmaf(y, z, x);
  y = __fadd_rn(y, 1.0f);
  int n = (int)fx;
  float p2n = __int_as_float((n + 127) << 23);
  return fmaxf(__fmul_rn(y, p2n), input);
}

// ------------------------------------------------------------------- kernels
// prep4: 4 px/thread. Reads all 8 channels as float4; computes dH_NN
// (Eigen no-FMA k-ascending chain, bias after — bit-exact as round 2),
// writes dHNN parity-packed: half[sub] entry q=(b<<19)|(y<<9)|(x>>1).
// Optionally passes X ch1..7 through to out. ids as u8 (linear layout).
template <int WRITE_OUT>
__global__ __launch_bounds__(256) void prep4(const float* __restrict__ X,
                                             const float* __restrict__ W,
                                             const float* __restrict__ Bb,
                                             float* __restrict__ dHNN,
                                             uint8_t* __restrict__ ids,
                                             float* __restrict__ out) {
  int tid = blockIdx.x * 256 + threadIdx.x;   // 0 .. BHW/4-1
  int e   = tid << 2;                          // pixel base (x0 multiple of 4)
  int b   = e >> 20;
  int yx  = e & (HW - 1);
  int y   = yx >> 10;
  int x0  = yx & 1023;
  int q4  = yx >> 2;                           // float4 index within plane
  const float4* xb = (const float4*)(X + ((size_t)b << 23));
  float4 xc[8];
#pragma unroll
  for (int c = 0; c < 8; c++) xc[c] = xb[(c << 18) + q4];
  if (WRITE_OUT) {
    float4* ob = (float4*)(out + ((size_t)b << 23));
#pragma unroll
    for (int c = 1; c < 8; c++) ob[(c << 18) + q4] = xc[c];
  }
#pragma unroll
  for (int j = 0; j < 4; j++) {
    float4 r;
#pragma unroll
    for (int o = 0; o < 4; o++) {
      float acc = 0.0f;
#pragma unroll
      for (int c = 0; c < 8; c++)
        acc = __fadd_rn(acc, __fmul_rn(((const float*)&xc[c])[j], W[o * 8 + c]));
      ((float*)&r)[o] = __fadd_rn(acc, Bb[o]);
    }
    int xj  = x0 + j;
    int sub = (y + xj) & 1;
    int q   = (b << 19) | (y << 9) | (xj >> 1);
    ((float4*)dHNN)[sub * NHu + (uint32_t)q] = r;
  }
  uchar4 v;
  v.x = (uint8_t)(int)((const float*)&xc[0])[0];
  v.y = (uint8_t)(int)((const float*)&xc[0])[1];
  v.z = (uint8_t)(int)((const float*)&xc[0])[2];
  v.w = (uint8_t)(int)((const float*)&xc[0])[3];
  *(uchar4*)(ids + e) = v;
}

// half_step: thread t IS the packed parity index -> coalesced float4 dHNN read.
// In-place ids update: active pixel's neighbors are opposite parity (race-free).
__global__ __launch_bounds__(256) void half_step(uint8_t* __restrict__ ids,
                                                 const float* __restrict__ dHNN,
                                                 uint32_t dk0, uint32_t dk1,
                                                 uint32_t uk0, uint32_t uk1,
                                                 int sub) {
  int t = blockIdx.x * 256 + threadIdx.x;     // 0 .. NH-1 (== packed index)
  int b = t >> 19;
  int r = t & 524287;
  int y = r >> 9;
  int i = r & 511;
  int x = (i << 1) | ((y + sub) & 1);         // (y+x)%2 == sub
  int p = (b << 20) | (y << 10) | x;

  float4 dnn = ((const float4*)dHNN)[sub * NHu + (uint32_t)t];

  uint32_t d0, d1, u0, u1;
  tf2x32(dk0, dk1, 0u, (uint32_t)p, d0, d1);  // randint lower_bits
  uint32_t db = d0 ^ d1;
  tf2x32(uk0, uk1, 0u, (uint32_t)p, u0, u1);  // uniform bits
  uint32_t ub = u0 ^ u1;
  int   dir = (int)(db & 3u);
  float u   = __fsub_rn(__uint_as_float((ub >> 9) | 0x3F800000u), 1.0f);

  int yN = (y + 1) & 1023, yP = (y - 1) & 1023;
  int xN = (x + 1) & 1023, xP = (x - 1) & 1023;
  int base = b << 20;
  uint32_t c  = ids[p];
  uint32_t n0 = ids[base + (yN << 10) + x];   // roll(-1,0): ids[y+1]
  uint32_t n1 = ids[base + (yP << 10) + x];   // roll(+1,0): ids[y-1]
  uint32_t n2 = ids[base + (y << 10) + xN];   // roll(0,-1): ids[x+1]
  uint32_t n3 = ids[base + (y << 10) + xP];   // roll(0,+1): ids[x-1]
  uint32_t s  = (dir == 0) ? n0 : (dir == 1) ? n1 : (dir == 2) ? n2 : n3;
  float dH_nn = (dir == 0) ? dnn.x : (dir == 1) ? dnn.y : (dir == 2) ? dnn.z : dnn.w;
  int dadh = ((int)(n0 != s) + (n1 != s) + (n2 != s) + (n3 != s))
           - ((int)(n0 != c) + (n1 != c) + (n2 != c) + (n3 != c));
  float dH = __fadd_rn((float)dadh, dH_nn);
  if (u < xla_expf(-dH)) ids[p] = (uint8_t)s;
}

// finalize_ch0: out channel 0 <- ids (4 px/thread).
__global__ __launch_bounds__(256) void finalize_ch0(const uint8_t* __restrict__ ids,
                                                    float* __restrict__ out) {
  int tid = blockIdx.x * 256 + threadIdx.x;   // 0 .. BHW/4-1
  int e   = tid << 2;
  int b   = e >> 20;
  int yx  = e & (HW - 1);
  uchar4 v = *(const uchar4*)(ids + e);
  float4 r;
  r.x = (float)v.x; r.y = (float)v.y; r.z = (float)v.z; r.w = (float)v.w;
  ((float4*)(out + ((size_t)b << 23)))[yx >> 2] = r;
}

// finalize_full: fallback (dHNN lived in out) — rewrite all of out from X+ids.
__global__ __launch_bounds__(256) void finalize_full(const float* __restrict__ X,
                                                     const uint8_t* __restrict__ ids,
                                                     float* __restrict__ out) {
  int t = blockIdx.x * 256 + threadIdx.x;
  int e = t << 2;
  int c = (e >> 20) & 7;
  float4 r;
  if (c == 0) {
    int b  = e >> 23;
    int yx = e & (HW - 1);
    uchar4 v = *(const uchar4*)(ids + ((size_t)b << 20) + yx);
    r.x = (float)v.x; r.y = (float)v.y; r.z = (float)v.z; r.w = (float)v.w;
  } else {
    r = ((const float4*)X)[t];
  }
  ((float4*)out)[t] = r;
}

// --------------------------------------------------------------------- host
extern "C" void kernel_launch(void* const* d_in, const int* in_sizes, int n_in,
                              void* d_out, int out_size, void* d_ws, size_t ws_size,
                              hipStream_t stream) {
  const float* X  = (const float*)d_in[0];
  const float* W  = (const float*)d_in[1];
  const float* Bb = (const float*)d_in[2];
  float* out = (float*)d_out;

  const size_t DHNN_BYTES = (size_t)BHWu * 16u;       // 134 MB
  const size_t IDS_BYTES  = (size_t)BHWu;             // 8.4 MB
  bool ws_ok = ws_size >= DHNN_BYTES + IDS_BYTES;

  float*   dHNN = ws_ok ? (float*)d_ws : out;
  uint8_t* ids  = ws_ok ? (uint8_t*)d_ws + DHNN_BYTES : (uint8_t*)d_ws;

  if (ws_ok) prep4<1><<<8192, 256, 0, stream>>>(X, W, Bb, dHNN, ids, out);
  else       prep4<0><<<8192, 256, 0, stream>>>(X, W, Bb, dHNN, ids, out);

  // Host-side threefry key chain (partitionable stream; verified round 2).
  uint32_t bk0 = 0u, bk1 = 42u;                        // jax.random.key(42)
  uint32_t keys[8][2];
  for (uint32_t t = 0; t < 8; t++)
    tf2x32(bk0, bk1, 0u, t, keys[t][0], keys[t][1]);   // fold-like split
  for (int t = 0; t < 8; t++) {
    uint32_t dk0, dk1, uk0, uk1, k1a, k1b;
    tf2x32(keys[t][0], keys[t][1], 0u, 0u, k1a, k1b);  // k1 (randint arg key)
    tf2x32(keys[t][0], keys[t][1], 0u, 1u, uk0, uk1);  // k2 (uniform key)
    tf2x32(k1a, k1b, 0u, 1u, dk0, dk1);                // randint internal kk2
    half_step<<<16384, 256, 0, stream>>>(ids, dHNN, dk0, dk1, uk0, uk1, t & 1);
  }

  if (ws_ok) finalize_ch0<<<8192, 256, 0, stream>>>(ids, out);
  else       finalize_full<<<65536, 256, 0, stream>>>(X, ids, out);
  (void)in_sizes; (void)n_in; (void)out_size;
}